// Round 12
// baseline (435.290 us; speedup 1.0000x reference)
//
#include <hip/hip_runtime.h>

#define DD 128
#define D2 256

typedef __attribute__((ext_vector_type(8))) short bf16x8;
typedef __attribute__((ext_vector_type(8))) unsigned short us8;
typedef __attribute__((ext_vector_type(4))) float f32x4;
typedef __attribute__((ext_vector_type(4))) unsigned short us4;
typedef __attribute__((ext_vector_type(4))) int i32x4;

#define MFMA16(a,b,c) __builtin_amdgcn_mfma_f32_16x16x32_bf16(a,b,c,0,0,0)

__device__ __forceinline__ unsigned short f2bf(float f) {
    unsigned int u = __float_as_uint(f);
    u += 0x7FFF + ((u >> 16) & 1);
    return (unsigned short)(u >> 16);
}
__device__ __forceinline__ float bf2f(unsigned short b) {
    return __uint_as_float(((unsigned int)b) << 16);
}

// ------- setup: zero deg | x->bf16 | weight pack | histogram | ea L3-warm -------
__global__ __launch_bounds__(256) void setup_kernel(
    int* __restrict__ deg, int n4,
    const float* __restrict__ x, unsigned short* __restrict__ xb, int n8,
    const float* __restrict__ w1a, const float* __restrict__ w1b,
    const float* __restrict__ w2a, const float* __restrict__ w2b,
    const float* __restrict__ wl,
    unsigned short* __restrict__ o1a, unsigned short* __restrict__ o1b,
    unsigned short* __restrict__ o2a, unsigned short* __restrict__ o2b,
    unsigned short* __restrict__ ol,
    const int* __restrict__ dstv, int E,
    const float* __restrict__ eaw, long totalF,
    int gz, int gcvt, int gw, int gE)
{
    int b = blockIdx.x;
    if (b < gz) {
        int i = b * 256 + threadIdx.x;
        if (i < n4) *(i32x4*)(deg + (size_t)i * 4) = (i32x4){0, 0, 0, 0};
    } else if (b < gz + gcvt) {
        int i = (b - gz) * 256 + threadIdx.x;
        if (i >= n8) return;
        f32x4 a = *(const f32x4*)(x + (size_t)i * 8);
        f32x4 c = *(const f32x4*)(x + (size_t)i * 8 + 4);
        us8 o = {f2bf(a.x), f2bf(a.y), f2bf(a.z), f2bf(a.w),
                 f2bf(c.x), f2bf(c.y), f2bf(c.z), f2bf(c.w)};
        *(us8*)(xb + (size_t)i * 8) = o;
    } else if (b < gz + gcvt + gw) {
        int rel = b - gz - gcvt;
        int widx = rel >> 4;
        int f = (rel & 15) * 4 + (threadIdx.x >> 6);
        int lane = threadIdx.x & 63;
        const float* W; unsigned short* O; int nks, Nc;
        switch (widx) {
            case 0: W = w1a; O = o1a; nks = 4; Nc = 256; break;
            case 1: W = w1b; O = o1b; nks = 8; Nc = 128; break;
            case 2: W = w2a; O = o2a; nks = 4; Nc = 256; break;
            case 3: W = w2b; O = o2b; nks = 8; Nc = 128; break;
            default: W = wl; O = ol;  nks = 8; Nc = 128; break;
        }
        int cf = f / nks, ks = f % nks;
        int col = cf * 16 + (lane & 15);
        int k0 = ks * 32 + (lane >> 4) * 8;
        unsigned short t[8];
        #pragma unroll
        for (int j = 0; j < 8; ++j) t[j] = f2bf(W[(size_t)(k0 + j) * Nc + col]);
        us4* dstp = (us4*)(O + ((size_t)f * 64 + lane) * 8);
        dstp[0] = (us4){t[0], t[1], t[2], t[3]};
        dstp[1] = (us4){t[4], t[5], t[6], t[7]};
    } else if (b < gz + gcvt + gw + gE) {
        int e = (b - gz - gcvt - gw) * 256 + threadIdx.x;
        if (e < E) atomicAdd(&deg[dstv[e]], 1);
    } else {
        // L3 warm: sequential touch of ea so agg1's random reads hit Infinity Cache
        long rel = b - gz - gcvt - gw - gE;
        long base = rel * 8192 + (long)threadIdx.x * 4;
        float s = 0.f;
        #pragma unroll
        for (int k = 0; k < 8; ++k) {
            long i = base + (long)k * 1024;
            if (i + 3 < totalF) {
                f32x4 v = *(const f32x4*)(eaw + i);
                s += v.x + v.y + v.z + v.w;
            }
        }
        asm volatile("" :: "v"(s));   // keep the loads live (no DCE)
    }
}

// ---------------- CSR scan ----------------
__global__ __launch_bounds__(256) void deg_blocksum(
    const int* __restrict__ deg, int* __restrict__ bsum, int Nn)
{
    __shared__ int ws[4];
    int b = blockIdx.x, t = threadIdx.x, lane = t & 63, w = t >> 6;
    int i0 = b * 1024 + t * 4;
    int s = 0;
    if (i0 + 3 < Nn) { int4 v = *(const int4*)(deg + i0); s = v.x + v.y + v.z + v.w; }
    else { for (int j = 0; j < 4; ++j) if (i0 + j < Nn) s += deg[i0 + j]; }
    #pragma unroll
    for (int o = 32; o >= 1; o >>= 1) s += __shfl_xor(s, o, 64);
    if (lane == 0) ws[w] = s;
    __syncthreads();
    if (t == 0) bsum[b] = ws[0] + ws[1] + ws[2] + ws[3];
}

__global__ __launch_bounds__(64) void scan_bsums(
    const int* __restrict__ bsum, int* __restrict__ boff, int nb,
    int* __restrict__ offs, int Nn)
{
    int lane = threadIdx.x;
    int v = (lane < nb) ? bsum[lane] : 0;
    int inc = v;
    #pragma unroll
    for (int o = 1; o < 64; o <<= 1) { int n = __shfl_up(inc, o, 64); if (lane >= o) inc += n; }
    if (lane < nb) boff[lane] = inc - v;
    if (lane == 63) offs[Nn] = inc;
}

__global__ __launch_bounds__(256) void scan_final(
    const int* __restrict__ deg, const int* __restrict__ boff,
    int* __restrict__ offs, int* __restrict__ cursor, int Nn)
{
    __shared__ int wsum[4];
    int b = blockIdx.x, t = threadIdx.x, lane = t & 63, w = t >> 6;
    int i0 = b * 1024 + t * 4;
    int a = 0, bb = 0, c = 0, d = 0;
    if (i0 + 3 < Nn) { int4 v = *(const int4*)(deg + i0); a = v.x; bb = v.y; c = v.z; d = v.w; }
    else {
        if (i0     < Nn) a  = deg[i0];
        if (i0 + 1 < Nn) bb = deg[i0 + 1];
        if (i0 + 2 < Nn) c  = deg[i0 + 2];
    }
    int tot = a + bb + c + d, inc = tot;
    #pragma unroll
    for (int o = 1; o < 64; o <<= 1) { int n = __shfl_up(inc, o, 64); if (lane >= o) inc += n; }
    if (lane == 63) wsum[w] = inc;
    __syncthreads();
    int wbase = 0;
    #pragma unroll
    for (int j = 0; j < 4; ++j) if (j < w) wbase += wsum[j];
    int excl = boff[b] + wbase + inc - tot;
    if (i0     < Nn) { offs[i0]     = excl;               cursor[i0]     = excl; }
    if (i0 + 1 < Nn) { offs[i0 + 1] = excl + a;           cursor[i0 + 1] = excl + a; }
    if (i0 + 2 < Nn) { offs[i0 + 2] = excl + a + bb;      cursor[i0 + 2] = excl + a + bb; }
    if (i0 + 3 < Nn) { offs[i0 + 3] = excl + a + bb + c;  cursor[i0 + 3] = excl + a + bb + c; }
}

__global__ __launch_bounds__(256) void fill_kernel(
    const int* __restrict__ src, const int* __restrict__ dst,
    int* __restrict__ cursor, int* __restrict__ eids,
    int* __restrict__ srcs, int E)
{
    int e = blockIdx.x * 256 + threadIdx.x;
    if (e < E) {
        int d = dst[e];
        int p = atomicAdd(&cursor[d], 1);
        eids[p] = e;
        srcs[p] = src[e];
    }
}

// --------- aggregate conv1: random ea read (L3-warmed), eab write cacheable ---------
__global__ __launch_bounds__(256) void aggregate_conv1(
    const unsigned short* __restrict__ xb, const float* __restrict__ ea,
    unsigned short* __restrict__ eab, const int* __restrict__ srcs,
    const int* __restrict__ eids, const int* __restrict__ offs,
    unsigned short* __restrict__ aggb, int Nn)
{
    int node = blockIdx.x * 4 + (threadIdx.x >> 6);
    if (node >= Nn) return;
    int lane = threadIdx.x & 63;
    int g = lane >> 4, c8 = (lane & 15) * 8;
    int beg = offs[node], deg = offs[node + 1] - beg;
    float acc[8] = {};
    if (g == 0) {
        us8 xv = *(const us8*)(xb + (size_t)node * DD + c8);
        #pragma unroll
        for (int j = 0; j < 8; ++j) acc[j] = bf2f(xv[j]);
    }
    for (int base = 0; base < deg; base += 16) {
        int  iu[4]; bool act[4]; int eu[4], su[4];
        #pragma unroll
        for (int u = 0; u < 4; ++u) {
            iu[u] = base + u * 4 + g;
            act[u] = iu[u] < deg;
            if (act[u]) { int pos = beg + iu[u]; eu[u] = eids[pos]; su[u] = srcs[pos]; }
        }
        f32x4 e0[4], e1[4]; us8 xv[4];
        #pragma unroll
        for (int u = 0; u < 4; ++u) {
            if (act[u]) {
                const float* ep = ea + (size_t)eu[u] * DD + c8;
                e0[u] = *(const f32x4*)ep;        // cacheable: L3-warmed
                e1[u] = *(const f32x4*)(ep + 4);
                xv[u] = *(const us8*)(xb + (size_t)su[u] * DD + c8);
            }
        }
        #pragma unroll
        for (int u = 0; u < 4; ++u) {
            if (act[u]) {
                int pos = beg + iu[u];
                us8 eb = {f2bf(e0[u].x), f2bf(e0[u].y), f2bf(e0[u].z), f2bf(e0[u].w),
                          f2bf(e1[u].x), f2bf(e1[u].y), f2bf(e1[u].z), f2bf(e1[u].w)};
                *(us8*)(eab + (size_t)pos * DD + c8) = eb;   // L3-resident for conv2
                acc[0] += fmaxf(bf2f(xv[u][0]) + e0[u].x, 0.f);
                acc[1] += fmaxf(bf2f(xv[u][1]) + e0[u].y, 0.f);
                acc[2] += fmaxf(bf2f(xv[u][2]) + e0[u].z, 0.f);
                acc[3] += fmaxf(bf2f(xv[u][3]) + e0[u].w, 0.f);
                acc[4] += fmaxf(bf2f(xv[u][4]) + e1[u].x, 0.f);
                acc[5] += fmaxf(bf2f(xv[u][5]) + e1[u].y, 0.f);
                acc[6] += fmaxf(bf2f(xv[u][6]) + e1[u].z, 0.f);
                acc[7] += fmaxf(bf2f(xv[u][7]) + e1[u].w, 0.f);
            }
        }
    }
    #pragma unroll
    for (int j = 0; j < 8; ++j) {
        acc[j] += __shfl_xor(acc[j], 16, 64);
        acc[j] += __shfl_xor(acc[j], 32, 64);
    }
    if (g == 0) {
        us8 o = {f2bf(acc[0]), f2bf(acc[1]), f2bf(acc[2]), f2bf(acc[3]),
                 f2bf(acc[4]), f2bf(acc[5]), f2bf(acc[6]), f2bf(acc[7])};
        *(us8*)(aggb + (size_t)node * DD + c8) = o;
    }
}

// --------- aggregate conv2: sequential eab (L3-hit) + srcs, h gather ---------
__global__ __launch_bounds__(256) void aggregate_conv2(
    const unsigned short* __restrict__ hb, const unsigned short* __restrict__ eab,
    const int* __restrict__ srcs, const int* __restrict__ offs,
    unsigned short* __restrict__ aggb, int Nn)
{
    int node = blockIdx.x * 4 + (threadIdx.x >> 6);
    if (node >= Nn) return;
    int lane = threadIdx.x & 63;
    int g = lane >> 4, c8 = (lane & 15) * 8;
    int beg = offs[node], deg = offs[node + 1] - beg;
    float acc[8] = {};
    if (g == 0) {
        us8 xv = *(const us8*)(hb + (size_t)node * DD + c8);
        #pragma unroll
        for (int j = 0; j < 8; ++j) acc[j] = bf2f(xv[j]);
    }
    for (int base = 0; base < deg; base += 16) {
        int iu[4]; bool act[4]; int su[4];
        #pragma unroll
        for (int u = 0; u < 4; ++u) {
            iu[u] = base + u * 4 + g;
            act[u] = iu[u] < deg;
            if (act[u]) su[u] = srcs[beg + iu[u]];
        }
        us8 ev[4], xv[4];
        #pragma unroll
        for (int u = 0; u < 4; ++u) {
            if (act[u]) {
                ev[u] = *(const us8*)(eab + (size_t)(beg + iu[u]) * DD + c8);
                xv[u] = *(const us8*)(hb + (size_t)su[u] * DD + c8);
            }
        }
        #pragma unroll
        for (int u = 0; u < 4; ++u) {
            if (act[u]) {
                #pragma unroll
                for (int j = 0; j < 8; ++j)
                    acc[j] += fmaxf(bf2f(xv[u][j]) + bf2f(ev[u][j]), 0.f);
            }
        }
    }
    #pragma unroll
    for (int j = 0; j < 8; ++j) {
        acc[j] += __shfl_xor(acc[j], 16, 64);
        acc[j] += __shfl_xor(acc[j], 32, 64);
    }
    if (g == 0) {
        us8 o = {f2bf(acc[0]), f2bf(acc[1]), f2bf(acc[2]), f2bf(acc[3]),
                 f2bf(acc[4]), f2bf(acc[5]), f2bf(acc[6]), f2bf(acc[7])};
        *(us8*)(aggb + (size_t)node * DD + c8) = o;
    }
}

// ------------- fused conv MLP (+optional final linear), 32 rows/wave -------------
template<int FUSE_FINAL>
__global__ __launch_bounds__(256) void conv_fused(
    const unsigned short* __restrict__ A, const unsigned short* __restrict__ WfA,
    const float* __restrict__ bA, const float* __restrict__ gA, const float* __restrict__ beA,
    const unsigned short* __restrict__ WfB,
    const float* __restrict__ bB, const float* __restrict__ gO, const float* __restrict__ bO,
    unsigned short* __restrict__ outb,
    const unsigned short* __restrict__ H1, const unsigned short* __restrict__ WfL,
    const float* __restrict__ bL, float* __restrict__ outf, int Nn)
{
    __shared__ unsigned char lds_all[4][16384];
    const int lane = threadIdx.x & 63;
    const int wid = threadIdx.x >> 6;
    unsigned char* my = lds_all[wid];
    const int rb = (blockIdx.x * 4 + wid) * 32;
    const int rlo = lane & 15, khi = lane >> 4;
    const int r0 = rb + rlo, r1 = rb + 16 + rlo;
    const size_t rr0 = (size_t)min(r0, Nn - 1), rr1 = (size_t)min(r1, Nn - 1);
    const int xw = (rlo & 7) << 4;

    // ---------------- stage A ----------------
    {
        bf16x8 aF0[4], aF1[4];
        #pragma unroll
        for (int ks = 0; ks < 4; ++ks) {
            aF0[ks] = *(const bf16x8*)(A + rr0 * DD + ks * 32 + khi * 8);
            aF1[ks] = *(const bf16x8*)(A + rr1 * DD + ks * 32 + khi * 8);
        }
        f32x4 acc0[16], acc1[16];
        #pragma unroll
        for (int cf = 0; cf < 16; ++cf) {
            acc0[cf] = (f32x4){0.f, 0.f, 0.f, 0.f};
            acc1[cf] = (f32x4){0.f, 0.f, 0.f, 0.f};
        }
        #pragma unroll
        for (int cf = 0; cf < 16; ++cf) {
            #pragma unroll
            for (int ks = 0; ks < 4; ++ks) {
                bf16x8 wv = *(const bf16x8*)(WfA + ((size_t)(cf * 4 + ks) * 64 + lane) * 8);
                acc0[cf] = MFMA16(wv, aF0[ks], acc0[cf]);
                acc1[cf] = MFMA16(wv, aF1[ks], acc1[cf]);
            }
        }
        float s0 = 0.f, q0 = 0.f, s1 = 0.f, q1 = 0.f;
        #pragma unroll
        for (int cf = 0; cf < 16; ++cf) {
            f32x4 bv = *(const f32x4*)(bA + cf * 16 + khi * 4);
            acc0[cf].x += bv.x; acc0[cf].y += bv.y; acc0[cf].z += bv.z; acc0[cf].w += bv.w;
            acc1[cf].x += bv.x; acc1[cf].y += bv.y; acc1[cf].z += bv.z; acc1[cf].w += bv.w;
            s0 += acc0[cf].x + acc0[cf].y + acc0[cf].z + acc0[cf].w;
            q0 += acc0[cf].x * acc0[cf].x + acc0[cf].y * acc0[cf].y + acc0[cf].z * acc0[cf].z + acc0[cf].w * acc0[cf].w;
            s1 += acc1[cf].x + acc1[cf].y + acc1[cf].z + acc1[cf].w;
            q1 += acc1[cf].x * acc1[cf].x + acc1[cf].y * acc1[cf].y + acc1[cf].z * acc1[cf].z + acc1[cf].w * acc1[cf].w;
        }
        s0 += __shfl_xor(s0, 16, 64); s0 += __shfl_xor(s0, 32, 64);
        q0 += __shfl_xor(q0, 16, 64); q0 += __shfl_xor(q0, 32, 64);
        s1 += __shfl_xor(s1, 16, 64); s1 += __shfl_xor(s1, 32, 64);
        q1 += __shfl_xor(q1, 16, 64); q1 += __shfl_xor(q1, 32, 64);
        const float m0 = s0 * (1.f / D2), m1 = s1 * (1.f / D2);
        const float rs0 = rsqrtf(q0 * (1.f / D2) - m0 * m0 + 1e-5f);
        const float rs1 = rsqrtf(q1 * (1.f / D2) - m1 * m1 + 1e-5f);
        #pragma unroll
        for (int cf = 0; cf < 16; ++cf) {
            f32x4 gv = *(const f32x4*)(gA + cf * 16 + khi * 4);
            f32x4 ev = *(const f32x4*)(beA + cf * 16 + khi * 4);
            us4 o0 = {f2bf(fmaxf((acc0[cf].x - m0) * rs0 * gv.x + ev.x, 0.f)),
                      f2bf(fmaxf((acc0[cf].y - m0) * rs0 * gv.y + ev.y, 0.f)),
                      f2bf(fmaxf((acc0[cf].z - m0) * rs0 * gv.z + ev.z, 0.f)),
                      f2bf(fmaxf((acc0[cf].w - m0) * rs0 * gv.w + ev.w, 0.f))};
            us4 o1 = {f2bf(fmaxf((acc1[cf].x - m1) * rs1 * gv.x + ev.x, 0.f)),
                      f2bf(fmaxf((acc1[cf].y - m1) * rs1 * gv.y + ev.y, 0.f)),
                      f2bf(fmaxf((acc1[cf].z - m1) * rs1 * gv.z + ev.z, 0.f)),
                      f2bf(fmaxf((acc1[cf].w - m1) * rs1 * gv.w + ev.w, 0.f))};
            int colb = (cf * 32 + khi * 8) ^ xw;
            *(us4*)(my + rlo * 512 + colb) = o0;
            *(us4*)(my + (16 + rlo) * 512 + colb) = o1;
        }
    }

    // ---------------- stage B ----------------
    float z0[8][4], z1[8][4];
    {
        bf16x8 bF0[8], bF1[8];
        #pragma unroll
        for (int ks = 0; ks < 8; ++ks) {
            int colb = (ks * 64 + khi * 16) ^ xw;
            bF0[ks] = *(const bf16x8*)(my + rlo * 512 + colb);
            bF1[ks] = *(const bf16x8*)(my + (16 + rlo) * 512 + colb);
        }
        f32x4 acc0[8], acc1[8];
        #pragma unroll
        for (int cf = 0; cf < 8; ++cf) {
            acc0[cf] = (f32x4){0.f, 0.f, 0.f, 0.f};
            acc1[cf] = (f32x4){0.f, 0.f, 0.f, 0.f};
        }
        #pragma unroll
        for (int cf = 0; cf < 8; ++cf) {
            #pragma unroll
            for (int ks = 0; ks < 8; ++ks) {
                bf16x8 wv = *(const bf16x8*)(WfB + ((size_t)(cf * 8 + ks) * 64 + lane) * 8);
                acc0[cf] = MFMA16(wv, bF0[ks], acc0[cf]);
                acc1[cf] = MFMA16(wv, bF1[ks], acc1[cf]);
            }
        }
        float s0 = 0.f, q0 = 0.f, s1 = 0.f, q1 = 0.f;
        #pragma unroll
        for (int cf = 0; cf < 8; ++cf) {
            f32x4 bv = *(const f32x4*)(bB + cf * 16 + khi * 4);
            acc0[cf].x = fmaxf(acc0[cf].x + bv.x, 0.f); acc0[cf].y = fmaxf(acc0[cf].y + bv.y, 0.f);
            acc0[cf].z = fmaxf(acc0[cf].z + bv.z, 0.f); acc0[cf].w = fmaxf(acc0[cf].w + bv.w, 0.f);
            acc1[cf].x = fmaxf(acc1[cf].x + bv.x, 0.f); acc1[cf].y = fmaxf(acc1[cf].y + bv.y, 0.f);
            acc1[cf].z = fmaxf(acc1[cf].z + bv.z, 0.f); acc1[cf].w = fmaxf(acc1[cf].w + bv.w, 0.f);
            s0 += acc0[cf].x + acc0[cf].y + acc0[cf].z + acc0[cf].w;
            q0 += acc0[cf].x * acc0[cf].x + acc0[cf].y * acc0[cf].y + acc0[cf].z * acc0[cf].z + acc0[cf].w * acc0[cf].w;
            s1 += acc1[cf].x + acc1[cf].y + acc1[cf].z + acc1[cf].w;
            q1 += acc1[cf].x * acc1[cf].x + acc1[cf].y * acc1[cf].y + acc1[cf].z * acc1[cf].z + acc1[cf].w * acc1[cf].w;
        }
        s0 += __shfl_xor(s0, 16, 64); s0 += __shfl_xor(s0, 32, 64);
        q0 += __shfl_xor(q0, 16, 64); q0 += __shfl_xor(q0, 32, 64);
        s1 += __shfl_xor(s1, 16, 64); s1 += __shfl_xor(s1, 32, 64);
        q1 += __shfl_xor(q1, 16, 64); q1 += __shfl_xor(q1, 32, 64);
        const float m0 = s0 * (1.f / DD), m1 = s1 * (1.f / DD);
        const float rs0 = rsqrtf(q0 * (1.f / DD) - m0 * m0 + 1e-5f);
        const float rs1 = rsqrtf(q1 * (1.f / DD) - m1 * m1 + 1e-5f);
        #pragma unroll
        for (int cf = 0; cf < 8; ++cf) {
            f32x4 gv = *(const f32x4*)(gO + cf * 16 + khi * 4);
            f32x4 ev = *(const f32x4*)(bO + cf * 16 + khi * 4);
            z0[cf][0] = (acc0[cf].x - m0) * rs0 * gv.x + ev.x;
            z0[cf][1] = (acc0[cf].y - m0) * rs0 * gv.y + ev.y;
            z0[cf][2] = (acc0[cf].z - m0) * rs0 * gv.z + ev.z;
            z0[cf][3] = (acc0[cf].w - m0) * rs0 * gv.w + ev.w;
            z1[cf][0] = (acc1[cf].x - m1) * rs1 * gv.x + ev.x;
            z1[cf][1] = (acc1[cf].y - m1) * rs1 * gv.y + ev.y;
            z1[cf][2] = (acc1[cf].z - m1) * rs1 * gv.z + ev.z;
            z1[cf][3] = (acc1[cf].w - m1) * rs1 * gv.w + ev.w;
        }
    }

    if constexpr (FUSE_FINAL == 0) {
        #pragma unroll
        for (int cf = 0; cf < 8; ++cf) {
            if (r0 < Nn) {
                us4 ob = {f2bf(z0[cf][0]), f2bf(z0[cf][1]), f2bf(z0[cf][2]), f2bf(z0[cf][3])};
                *(us4*)(outb + (size_t)r0 * DD + cf * 16 + khi * 4) = ob;
            }
            if (r1 < Nn) {
                us4 ob = {f2bf(z1[cf][0]), f2bf(z1[cf][1]), f2bf(z1[cf][2]), f2bf(z1[cf][3])};
                *(us4*)(outb + (size_t)r1 * DD + cf * 16 + khi * 4) = ob;
            }
        }
    } else {
        #pragma unroll
        for (int cf = 0; cf < 8; ++cf) {
            us4 o0 = {f2bf(z0[cf][0]), f2bf(z0[cf][1]), f2bf(z0[cf][2]), f2bf(z0[cf][3])};
            us4 o1 = {f2bf(z1[cf][0]), f2bf(z1[cf][1]), f2bf(z1[cf][2]), f2bf(z1[cf][3])};
            int colb = (cf * 32 + khi * 8) ^ xw;
            *(us4*)(my + rlo * 256 + colb) = o0;
            *(us4*)(my + (16 + rlo) * 256 + colb) = o1;
        }
        bf16x8 fF0[8], fF1[8];
        #pragma unroll
        for (int ks = 0; ks < 4; ++ks) {
            fF0[ks] = *(const bf16x8*)(H1 + rr0 * DD + ks * 32 + khi * 8);
            fF1[ks] = *(const bf16x8*)(H1 + rr1 * DD + ks * 32 + khi * 8);
            int colb = (ks * 64 + khi * 16) ^ xw;
            fF0[4 + ks] = *(const bf16x8*)(my + rlo * 256 + colb);
            fF1[4 + ks] = *(const bf16x8*)(my + (16 + rlo) * 256 + colb);
        }
        f32x4 acc0[8], acc1[8];
        #pragma unroll
        for (int cf = 0; cf < 8; ++cf) {
            acc0[cf] = (f32x4){0.f, 0.f, 0.f, 0.f};
            acc1[cf] = (f32x4){0.f, 0.f, 0.f, 0.f};
        }
        #pragma unroll
        for (int cf = 0; cf < 8; ++cf) {
            #pragma unroll
            for (int ks = 0; ks < 8; ++ks) {
                bf16x8 wv = *(const bf16x8*)(WfL + ((size_t)(cf * 8 + ks) * 64 + lane) * 8);
                acc0[cf] = MFMA16(wv, fF0[ks], acc0[cf]);
                acc1[cf] = MFMA16(wv, fF1[ks], acc1[cf]);
            }
        }
        #pragma unroll
        for (int cf = 0; cf < 8; ++cf) {
            f32x4 bv = *(const f32x4*)(bL + cf * 16 + khi * 4);
            if (r0 < Nn) {
                f32x4 o;
                o.x = fmaxf(acc0[cf].x + bv.x, 0.f);
                o.y = fmaxf(acc0[cf].y + bv.y, 0.f);
                o.z = fmaxf(acc0[cf].z + bv.z, 0.f);
                o.w = fmaxf(acc0[cf].w + bv.w, 0.f);
                *(f32x4*)(outf + (size_t)r0 * DD + cf * 16 + khi * 4) = o;
            }
            if (r1 < Nn) {
                f32x4 o;
                o.x = fmaxf(acc1[cf].x + bv.x, 0.f);
                o.y = fmaxf(acc1[cf].y + bv.y, 0.f);
                o.z = fmaxf(acc1[cf].z + bv.z, 0.f);
                o.w = fmaxf(acc1[cf].w + bv.w, 0.f);
                *(f32x4*)(outf + (size_t)r1 * DD + cf * 16 + khi * 4) = o;
            }
        }
    }
}

extern "C" void kernel_launch(void* const* d_in, const int* in_sizes, int n_in,
                              void* d_out, int out_size, void* d_ws, size_t ws_size,
                              hipStream_t stream)
{
    const float* x    = (const float*)d_in[0];
    const int*   ei   = (const int*)d_in[1];
    const float* ea   = (const float*)d_in[2];
    const float* w1a  = (const float*)d_in[4];
    const float* b1a  = (const float*)d_in[5];
    const float* g1a  = (const float*)d_in[6];
    const float* be1a = (const float*)d_in[7];
    const float* w1b  = (const float*)d_in[8];
    const float* b1b  = (const float*)d_in[9];
    const float* w2a  = (const float*)d_in[10];
    const float* b2a  = (const float*)d_in[11];
    const float* g2a  = (const float*)d_in[12];
    const float* be2a = (const float*)d_in[13];
    const float* w2b  = (const float*)d_in[14];
    const float* b2b  = (const float*)d_in[15];
    const float* ng1  = (const float*)d_in[16];
    const float* nb1  = (const float*)d_in[17];
    const float* ng2  = (const float*)d_in[18];
    const float* nb2  = (const float*)d_in[19];
    const float* wl   = (const float*)d_in[20];
    const float* bl   = (const float*)d_in[21];

    const int N = in_sizes[0] / DD;
    const int E = in_sizes[1] / 2;
    const int* src = ei;
    const int* dst = ei + E;

    char* wp = (char*)d_ws;
    auto alloc = [&](size_t bytes) { void* p = wp; wp += (bytes + 255) & ~(size_t)255; return p; };
    unsigned short* aggb = (unsigned short*)alloc((size_t)N * DD * 2);
    unsigned short* xb   = (unsigned short*)alloc((size_t)N * DD * 2);
    unsigned short* h1b  = (unsigned short*)alloc((size_t)N * DD * 2);
    unsigned short* eab  = (unsigned short*)alloc((size_t)E * DD * 2);
    unsigned short* WfA1 = (unsigned short*)alloc(32768 * 2);
    unsigned short* WfB1 = (unsigned short*)alloc(32768 * 2);
    unsigned short* WfA2 = (unsigned short*)alloc(32768 * 2);
    unsigned short* WfB2 = (unsigned short*)alloc(32768 * 2);
    unsigned short* WfL  = (unsigned short*)alloc(32768 * 2);
    int* deg    = (int*)alloc((size_t)(N + 4) * 4);
    int* offs   = (int*)alloc((size_t)(N + 1) * 4);
    int* cursor = (int*)alloc((size_t)N * 4);
    int* bsum   = (int*)alloc(64 * 4);
    int* boff   = (int*)alloc(64 * 4);
    int* eids   = (int*)alloc((size_t)E * 4);
    int* srcs   = (int*)alloc((size_t)E * 4);

    const int nb = (N + 1023) / 1024;
    const int gE = (E + 255) / 256;
    const int gagg = (N + 3) / 4;
    const int gg = (N + 127) / 128;
    const int n8 = N * 16;
    const int gcvt = (n8 + 255) / 256;
    const int n4 = (N + 3) / 4;
    const int gz = (n4 + 255) / 256;
    const long totalF = (long)E * DD;
    const int gwarm = (int)((totalF + 8191) / 8192);

    setup_kernel<<<gz + gcvt + 80 + gE + gwarm, 256, 0, stream>>>(
        deg, n4, x, xb, n8, w1a, w1b, w2a, w2b, wl,
        WfA1, WfB1, WfA2, WfB2, WfL, dst, E, ea, totalF, gz, gcvt, 80, gE);
    deg_blocksum<<<nb, 256, 0, stream>>>(deg, bsum, N);
    scan_bsums<<<1, 64, 0, stream>>>(bsum, boff, nb, offs, N);
    scan_final<<<nb, 256, 0, stream>>>(deg, boff, offs, cursor, N);
    fill_kernel<<<gE, 256, 0, stream>>>(src, dst, cursor, eids, srcs, E);

    // ---- conv1 (fused MLP) ----
    aggregate_conv1<<<gagg, 256, 0, stream>>>(xb, ea, eab, srcs, eids, offs, aggb, N);
    conv_fused<0><<<gg, 256, 0, stream>>>(aggb, WfA1, b1a, g1a, be1a,
                                          WfB1, b1b, ng1, nb1, h1b,
                                          nullptr, nullptr, nullptr, nullptr, N);

    // ---- conv2 (fused MLP + final linear) ----
    aggregate_conv2<<<gagg, 256, 0, stream>>>(h1b, eab, srcs, offs, aggb, N);
    conv_fused<1><<<gg, 256, 0, stream>>>(aggb, WfA2, b2a, g2a, be2a,
                                          WfB2, b2b, ng2, nb2, nullptr,
                                          h1b, WfL, bl, (float*)d_out, N);
}

// Round 13
// 346.874 us; speedup vs baseline: 1.2549x; 1.2549x over previous
//
#include <hip/hip_runtime.h>

#define DD 128
#define D2 256

typedef __attribute__((ext_vector_type(8))) short bf16x8;
typedef __attribute__((ext_vector_type(8))) unsigned short us8;
typedef __attribute__((ext_vector_type(4))) float f32x4;
typedef __attribute__((ext_vector_type(4))) unsigned short us4;
typedef __attribute__((ext_vector_type(4))) int i32x4;

#define MFMA16(a,b,c) __builtin_amdgcn_mfma_f32_16x16x32_bf16(a,b,c,0,0,0)

__device__ __forceinline__ unsigned short f2bf(float f) {
    unsigned int u = __float_as_uint(f);
    u += 0x7FFF + ((u >> 16) & 1);
    return (unsigned short)(u >> 16);
}
__device__ __forceinline__ float bf2f(unsigned short b) {
    return __uint_as_float(((unsigned int)b) << 16);
}

// ------- setup: zero deg | x->bf16 | weight pack | degree histogram (fused) -------
__global__ __launch_bounds__(256) void setup_kernel(
    int* __restrict__ deg, int n4,
    const float* __restrict__ x, unsigned short* __restrict__ xb, int n8,
    const float* __restrict__ w1a, const float* __restrict__ w1b,
    const float* __restrict__ w2a, const float* __restrict__ w2b,
    const float* __restrict__ wl,
    unsigned short* __restrict__ o1a, unsigned short* __restrict__ o1b,
    unsigned short* __restrict__ o2a, unsigned short* __restrict__ o2b,
    unsigned short* __restrict__ ol,
    const int* __restrict__ dstv, int E,
    int gz, int gcvt, int gw)
{
    int b = blockIdx.x;
    if (b < gz) {
        int i = b * 256 + threadIdx.x;
        if (i < n4) *(i32x4*)(deg + (size_t)i * 4) = (i32x4){0, 0, 0, 0};
    } else if (b < gz + gcvt) {
        int i = (b - gz) * 256 + threadIdx.x;
        if (i >= n8) return;
        f32x4 a = *(const f32x4*)(x + (size_t)i * 8);
        f32x4 c = *(const f32x4*)(x + (size_t)i * 8 + 4);
        us8 o = {f2bf(a.x), f2bf(a.y), f2bf(a.z), f2bf(a.w),
                 f2bf(c.x), f2bf(c.y), f2bf(c.z), f2bf(c.w)};
        *(us8*)(xb + (size_t)i * 8) = o;
    } else if (b < gz + gcvt + gw) {
        int rel = b - gz - gcvt;
        int widx = rel >> 4;
        int f = (rel & 15) * 4 + (threadIdx.x >> 6);
        int lane = threadIdx.x & 63;
        const float* W; unsigned short* O; int nks, Nc;
        switch (widx) {
            case 0: W = w1a; O = o1a; nks = 4; Nc = 256; break;
            case 1: W = w1b; O = o1b; nks = 8; Nc = 128; break;
            case 2: W = w2a; O = o2a; nks = 4; Nc = 256; break;
            case 3: W = w2b; O = o2b; nks = 8; Nc = 128; break;
            default: W = wl; O = ol;  nks = 8; Nc = 128; break;
        }
        int cf = f / nks, ks = f % nks;
        int col = cf * 16 + (lane & 15);
        int k0 = ks * 32 + (lane >> 4) * 8;
        unsigned short t[8];
        #pragma unroll
        for (int j = 0; j < 8; ++j) t[j] = f2bf(W[(size_t)(k0 + j) * Nc + col]);
        us4* dstp = (us4*)(O + ((size_t)f * 64 + lane) * 8);
        dstp[0] = (us4){t[0], t[1], t[2], t[3]};
        dstp[1] = (us4){t[4], t[5], t[6], t[7]};
    } else {
        int e = (b - gz - gcvt - gw) * 256 + threadIdx.x;
        if (e < E) atomicAdd(&deg[dstv[e]], 1);
    }
}

// ---------------- CSR scan ----------------
__global__ __launch_bounds__(256) void deg_blocksum(
    const int* __restrict__ deg, int* __restrict__ bsum, int Nn)
{
    __shared__ int ws[4];
    int b = blockIdx.x, t = threadIdx.x, lane = t & 63, w = t >> 6;
    int i0 = b * 1024 + t * 4;
    int s = 0;
    if (i0 + 3 < Nn) { int4 v = *(const int4*)(deg + i0); s = v.x + v.y + v.z + v.w; }
    else { for (int j = 0; j < 4; ++j) if (i0 + j < Nn) s += deg[i0 + j]; }
    #pragma unroll
    for (int o = 32; o >= 1; o >>= 1) s += __shfl_xor(s, o, 64);
    if (lane == 0) ws[w] = s;
    __syncthreads();
    if (t == 0) bsum[b] = ws[0] + ws[1] + ws[2] + ws[3];
}

__global__ __launch_bounds__(64) void scan_bsums(
    const int* __restrict__ bsum, int* __restrict__ boff, int nb,
    int* __restrict__ offs, int Nn)
{
    int lane = threadIdx.x;
    int v = (lane < nb) ? bsum[lane] : 0;
    int inc = v;
    #pragma unroll
    for (int o = 1; o < 64; o <<= 1) { int n = __shfl_up(inc, o, 64); if (lane >= o) inc += n; }
    if (lane < nb) boff[lane] = inc - v;
    if (lane == 63) offs[Nn] = inc;
}

__global__ __launch_bounds__(256) void scan_final(
    const int* __restrict__ deg, const int* __restrict__ boff,
    int* __restrict__ offs, int* __restrict__ cursor, int Nn)
{
    __shared__ int wsum[4];
    int b = blockIdx.x, t = threadIdx.x, lane = t & 63, w = t >> 6;
    int i0 = b * 1024 + t * 4;
    int a = 0, bb = 0, c = 0, d = 0;
    if (i0 + 3 < Nn) { int4 v = *(const int4*)(deg + i0); a = v.x; bb = v.y; c = v.z; d = v.w; }
    else {
        if (i0     < Nn) a  = deg[i0];
        if (i0 + 1 < Nn) bb = deg[i0 + 1];
        if (i0 + 2 < Nn) c  = deg[i0 + 2];
    }
    int tot = a + bb + c + d, inc = tot;
    #pragma unroll
    for (int o = 1; o < 64; o <<= 1) { int n = __shfl_up(inc, o, 64); if (lane >= o) inc += n; }
    if (lane == 63) wsum[w] = inc;
    __syncthreads();
    int wbase = 0;
    #pragma unroll
    for (int j = 0; j < 4; ++j) if (j < w) wbase += wsum[j];
    int excl = boff[b] + wbase + inc - tot;
    if (i0     < Nn) { offs[i0]     = excl;               cursor[i0]     = excl; }
    if (i0 + 1 < Nn) { offs[i0 + 1] = excl + a;           cursor[i0 + 1] = excl + a; }
    if (i0 + 2 < Nn) { offs[i0 + 2] = excl + a + bb;      cursor[i0 + 2] = excl + a + bb; }
    if (i0 + 3 < Nn) { offs[i0 + 3] = excl + a + bb + c;  cursor[i0 + 3] = excl + a + bb + c; }
}

__global__ __launch_bounds__(256) void fill_kernel(
    const int* __restrict__ src, const int* __restrict__ dst,
    int* __restrict__ cursor, int* __restrict__ eids,
    int* __restrict__ srcs, int E)
{
    int e = blockIdx.x * 256 + threadIdx.x;
    if (e < E) {
        int d = dst[e];
        int p = atomicAdd(&cursor[d], 1);
        eids[p] = e;
        srcs[p] = src[e];
    }
}

// --------- aggregate conv1: random ea read (nontemporal), eab write CACHEABLE (L3 for conv2) ---------
__global__ __launch_bounds__(256) void aggregate_conv1(
    const unsigned short* __restrict__ xb, const float* __restrict__ ea,
    unsigned short* __restrict__ eab, const int* __restrict__ srcs,
    const int* __restrict__ eids, const int* __restrict__ offs,
    unsigned short* __restrict__ aggb, int Nn)
{
    int node = blockIdx.x * 4 + (threadIdx.x >> 6);
    if (node >= Nn) return;
    int lane = threadIdx.x & 63;
    int g = lane >> 4, c8 = (lane & 15) * 8;
    int beg = offs[node], deg = offs[node + 1] - beg;
    float acc[8] = {};
    if (g == 0) {
        us8 xv = *(const us8*)(xb + (size_t)node * DD + c8);
        #pragma unroll
        for (int j = 0; j < 8; ++j) acc[j] = bf2f(xv[j]);
    }
    for (int base = 0; base < deg; base += 16) {
        int  iu[4]; bool act[4]; int eu[4], su[4];
        #pragma unroll
        for (int u = 0; u < 4; ++u) {
            iu[u] = base + u * 4 + g;
            act[u] = iu[u] < deg;
            if (act[u]) { int pos = beg + iu[u]; eu[u] = eids[pos]; su[u] = srcs[pos]; }
        }
        f32x4 e0[4], e1[4]; us8 xv[4];
        #pragma unroll
        for (int u = 0; u < 4; ++u) {
            if (act[u]) {
                const float* ep = ea + (size_t)eu[u] * DD + c8;
                e0[u] = __builtin_nontemporal_load((const f32x4*)ep);
                e1[u] = __builtin_nontemporal_load((const f32x4*)(ep + 4));
                xv[u] = *(const us8*)(xb + (size_t)su[u] * DD + c8);
            }
        }
        #pragma unroll
        for (int u = 0; u < 4; ++u) {
            if (act[u]) {
                int pos = beg + iu[u];
                us8 eb = {f2bf(e0[u].x), f2bf(e0[u].y), f2bf(e0[u].z), f2bf(e0[u].w),
                          f2bf(e1[u].x), f2bf(e1[u].y), f2bf(e1[u].z), f2bf(e1[u].w)};
                *(us8*)(eab + (size_t)pos * DD + c8) = eb;   // cacheable: L3-resident for conv2
                acc[0] += fmaxf(bf2f(xv[u][0]) + e0[u].x, 0.f);
                acc[1] += fmaxf(bf2f(xv[u][1]) + e0[u].y, 0.f);
                acc[2] += fmaxf(bf2f(xv[u][2]) + e0[u].z, 0.f);
                acc[3] += fmaxf(bf2f(xv[u][3]) + e0[u].w, 0.f);
                acc[4] += fmaxf(bf2f(xv[u][4]) + e1[u].x, 0.f);
                acc[5] += fmaxf(bf2f(xv[u][5]) + e1[u].y, 0.f);
                acc[6] += fmaxf(bf2f(xv[u][6]) + e1[u].z, 0.f);
                acc[7] += fmaxf(bf2f(xv[u][7]) + e1[u].w, 0.f);
            }
        }
    }
    #pragma unroll
    for (int j = 0; j < 8; ++j) {
        acc[j] += __shfl_xor(acc[j], 16, 64);
        acc[j] += __shfl_xor(acc[j], 32, 64);
    }
    if (g == 0) {
        us8 o = {f2bf(acc[0]), f2bf(acc[1]), f2bf(acc[2]), f2bf(acc[3]),
                 f2bf(acc[4]), f2bf(acc[5]), f2bf(acc[6]), f2bf(acc[7])};
        *(us8*)(aggb + (size_t)node * DD + c8) = o;
    }
}

// --------- aggregate conv2: sequential eab (L3-hit) + srcs, h gather ---------
__global__ __launch_bounds__(256) void aggregate_conv2(
    const unsigned short* __restrict__ hb, const unsigned short* __restrict__ eab,
    const int* __restrict__ srcs, const int* __restrict__ offs,
    unsigned short* __restrict__ aggb, int Nn)
{
    int node = blockIdx.x * 4 + (threadIdx.x >> 6);
    if (node >= Nn) return;
    int lane = threadIdx.x & 63;
    int g = lane >> 4, c8 = (lane & 15) * 8;
    int beg = offs[node], deg = offs[node + 1] - beg;
    float acc[8] = {};
    if (g == 0) {
        us8 xv = *(const us8*)(hb + (size_t)node * DD + c8);
        #pragma unroll
        for (int j = 0; j < 8; ++j) acc[j] = bf2f(xv[j]);
    }
    for (int base = 0; base < deg; base += 16) {
        int iu[4]; bool act[4]; int su[4];
        #pragma unroll
        for (int u = 0; u < 4; ++u) {
            iu[u] = base + u * 4 + g;
            act[u] = iu[u] < deg;
            if (act[u]) su[u] = srcs[beg + iu[u]];
        }
        us8 ev[4], xv[4];
        #pragma unroll
        for (int u = 0; u < 4; ++u) {
            if (act[u]) {
                ev[u] = *(const us8*)(eab + (size_t)(beg + iu[u]) * DD + c8);
                xv[u] = *(const us8*)(hb + (size_t)su[u] * DD + c8);
            }
        }
        #pragma unroll
        for (int u = 0; u < 4; ++u) {
            if (act[u]) {
                #pragma unroll
                for (int j = 0; j < 8; ++j)
                    acc[j] += fmaxf(bf2f(xv[u][j]) + bf2f(ev[u][j]), 0.f);
            }
        }
    }
    #pragma unroll
    for (int j = 0; j < 8; ++j) {
        acc[j] += __shfl_xor(acc[j], 16, 64);
        acc[j] += __shfl_xor(acc[j], 32, 64);
    }
    if (g == 0) {
        us8 o = {f2bf(acc[0]), f2bf(acc[1]), f2bf(acc[2]), f2bf(acc[3]),
                 f2bf(acc[4]), f2bf(acc[5]), f2bf(acc[6]), f2bf(acc[7])};
        *(us8*)(aggb + (size_t)node * DD + c8) = o;
    }
}

// ------------- fused conv MLP (+optional final linear), 32 rows/wave -------------
template<int FUSE_FINAL>
__global__ __launch_bounds__(256) void conv_fused(
    const unsigned short* __restrict__ A, const unsigned short* __restrict__ WfA,
    const float* __restrict__ bA, const float* __restrict__ gA, const float* __restrict__ beA,
    const unsigned short* __restrict__ WfB,
    const float* __restrict__ bB, const float* __restrict__ gO, const float* __restrict__ bO,
    unsigned short* __restrict__ outb,
    const unsigned short* __restrict__ H1, const unsigned short* __restrict__ WfL,
    const float* __restrict__ bL, float* __restrict__ outf, int Nn)
{
    __shared__ unsigned char lds_all[4][16384];
    const int lane = threadIdx.x & 63;
    const int wid = threadIdx.x >> 6;
    unsigned char* my = lds_all[wid];
    const int rb = (blockIdx.x * 4 + wid) * 32;
    const int rlo = lane & 15, khi = lane >> 4;
    const int r0 = rb + rlo, r1 = rb + 16 + rlo;
    const size_t rr0 = (size_t)min(r0, Nn - 1), rr1 = (size_t)min(r1, Nn - 1);
    const int xw = (rlo & 7) << 4;

    // ---------------- stage A ----------------
    {
        bf16x8 aF0[4], aF1[4];
        #pragma unroll
        for (int ks = 0; ks < 4; ++ks) {
            aF0[ks] = *(const bf16x8*)(A + rr0 * DD + ks * 32 + khi * 8);
            aF1[ks] = *(const bf16x8*)(A + rr1 * DD + ks * 32 + khi * 8);
        }
        f32x4 acc0[16], acc1[16];
        #pragma unroll
        for (int cf = 0; cf < 16; ++cf) {
            acc0[cf] = (f32x4){0.f, 0.f, 0.f, 0.f};
            acc1[cf] = (f32x4){0.f, 0.f, 0.f, 0.f};
        }
        #pragma unroll
        for (int cf = 0; cf < 16; ++cf) {
            #pragma unroll
            for (int ks = 0; ks < 4; ++ks) {
                bf16x8 wv = *(const bf16x8*)(WfA + ((size_t)(cf * 4 + ks) * 64 + lane) * 8);
                acc0[cf] = MFMA16(wv, aF0[ks], acc0[cf]);
                acc1[cf] = MFMA16(wv, aF1[ks], acc1[cf]);
            }
        }
        float s0 = 0.f, q0 = 0.f, s1 = 0.f, q1 = 0.f;
        #pragma unroll
        for (int cf = 0; cf < 16; ++cf) {
            f32x4 bv = *(const f32x4*)(bA + cf * 16 + khi * 4);
            acc0[cf].x += bv.x; acc0[cf].y += bv.y; acc0[cf].z += bv.z; acc0[cf].w += bv.w;
            acc1[cf].x += bv.x; acc1[cf].y += bv.y; acc1[cf].z += bv.z; acc1[cf].w += bv.w;
            s0 += acc0[cf].x + acc0[cf].y + acc0[cf].z + acc0[cf].w;
            q0 += acc0[cf].x * acc0[cf].x + acc0[cf].y * acc0[cf].y + acc0[cf].z * acc0[cf].z + acc0[cf].w * acc0[cf].w;
            s1 += acc1[cf].x + acc1[cf].y + acc1[cf].z + acc1[cf].w;
            q1 += acc1[cf].x * acc1[cf].x + acc1[cf].y * acc1[cf].y + acc1[cf].z * acc1[cf].z + acc1[cf].w * acc1[cf].w;
        }
        s0 += __shfl_xor(s0, 16, 64); s0 += __shfl_xor(s0, 32, 64);
        q0 += __shfl_xor(q0, 16, 64); q0 += __shfl_xor(q0, 32, 64);
        s1 += __shfl_xor(s1, 16, 64); s1 += __shfl_xor(s1, 32, 64);
        q1 += __shfl_xor(q1, 16, 64); q1 += __shfl_xor(q1, 32, 64);
        const float m0 = s0 * (1.f / D2), m1 = s1 * (1.f / D2);
        const float rs0 = rsqrtf(q0 * (1.f / D2) - m0 * m0 + 1e-5f);
        const float rs1 = rsqrtf(q1 * (1.f / D2) - m1 * m1 + 1e-5f);
        #pragma unroll
        for (int cf = 0; cf < 16; ++cf) {
            f32x4 gv = *(const f32x4*)(gA + cf * 16 + khi * 4);
            f32x4 ev = *(const f32x4*)(beA + cf * 16 + khi * 4);
            us4 o0 = {f2bf(fmaxf((acc0[cf].x - m0) * rs0 * gv.x + ev.x, 0.f)),
                      f2bf(fmaxf((acc0[cf].y - m0) * rs0 * gv.y + ev.y, 0.f)),
                      f2bf(fmaxf((acc0[cf].z - m0) * rs0 * gv.z + ev.z, 0.f)),
                      f2bf(fmaxf((acc0[cf].w - m0) * rs0 * gv.w + ev.w, 0.f))};
            us4 o1 = {f2bf(fmaxf((acc1[cf].x - m1) * rs1 * gv.x + ev.x, 0.f)),
                      f2bf(fmaxf((acc1[cf].y - m1) * rs1 * gv.y + ev.y, 0.f)),
                      f2bf(fmaxf((acc1[cf].z - m1) * rs1 * gv.z + ev.z, 0.f)),
                      f2bf(fmaxf((acc1[cf].w - m1) * rs1 * gv.w + ev.w, 0.f))};
            int colb = (cf * 32 + khi * 8) ^ xw;
            *(us4*)(my + rlo * 512 + colb) = o0;
            *(us4*)(my + (16 + rlo) * 512 + colb) = o1;
        }
    }

    // ---------------- stage B ----------------
    float z0[8][4], z1[8][4];
    {
        bf16x8 bF0[8], bF1[8];
        #pragma unroll
        for (int ks = 0; ks < 8; ++ks) {
            int colb = (ks * 64 + khi * 16) ^ xw;
            bF0[ks] = *(const bf16x8*)(my + rlo * 512 + colb);
            bF1[ks] = *(const bf16x8*)(my + (16 + rlo) * 512 + colb);
        }
        f32x4 acc0[8], acc1[8];
        #pragma unroll
        for (int cf = 0; cf < 8; ++cf) {
            acc0[cf] = (f32x4){0.f, 0.f, 0.f, 0.f};
            acc1[cf] = (f32x4){0.f, 0.f, 0.f, 0.f};
        }
        #pragma unroll
        for (int cf = 0; cf < 8; ++cf) {
            #pragma unroll
            for (int ks = 0; ks < 8; ++ks) {
                bf16x8 wv = *(const bf16x8*)(WfB + ((size_t)(cf * 8 + ks) * 64 + lane) * 8);
                acc0[cf] = MFMA16(wv, bF0[ks], acc0[cf]);
                acc1[cf] = MFMA16(wv, bF1[ks], acc1[cf]);
            }
        }
        float s0 = 0.f, q0 = 0.f, s1 = 0.f, q1 = 0.f;
        #pragma unroll
        for (int cf = 0; cf < 8; ++cf) {
            f32x4 bv = *(const f32x4*)(bB + cf * 16 + khi * 4);
            acc0[cf].x = fmaxf(acc0[cf].x + bv.x, 0.f); acc0[cf].y = fmaxf(acc0[cf].y + bv.y, 0.f);
            acc0[cf].z = fmaxf(acc0[cf].z + bv.z, 0.f); acc0[cf].w = fmaxf(acc0[cf].w + bv.w, 0.f);
            acc1[cf].x = fmaxf(acc1[cf].x + bv.x, 0.f); acc1[cf].y = fmaxf(acc1[cf].y + bv.y, 0.f);
            acc1[cf].z = fmaxf(acc1[cf].z + bv.z, 0.f); acc1[cf].w = fmaxf(acc1[cf].w + bv.w, 0.f);
            s0 += acc0[cf].x + acc0[cf].y + acc0[cf].z + acc0[cf].w;
            q0 += acc0[cf].x * acc0[cf].x + acc0[cf].y * acc0[cf].y + acc0[cf].z * acc0[cf].z + acc0[cf].w * acc0[cf].w;
            s1 += acc1[cf].x + acc1[cf].y + acc1[cf].z + acc1[cf].w;
            q1 += acc1[cf].x * acc1[cf].x + acc1[cf].y * acc1[cf].y + acc1[cf].z * acc1[cf].z + acc1[cf].w * acc1[cf].w;
        }
        s0 += __shfl_xor(s0, 16, 64); s0 += __shfl_xor(s0, 32, 64);
        q0 += __shfl_xor(q0, 16, 64); q0 += __shfl_xor(q0, 32, 64);
        s1 += __shfl_xor(s1, 16, 64); s1 += __shfl_xor(s1, 32, 64);
        q1 += __shfl_xor(q1, 16, 64); q1 += __shfl_xor(q1, 32, 64);
        const float m0 = s0 * (1.f / DD), m1 = s1 * (1.f / DD);
        const float rs0 = rsqrtf(q0 * (1.f / DD) - m0 * m0 + 1e-5f);
        const float rs1 = rsqrtf(q1 * (1.f / DD) - m1 * m1 + 1e-5f);
        #pragma unroll
        for (int cf = 0; cf < 8; ++cf) {
            f32x4 gv = *(const f32x4*)(gO + cf * 16 + khi * 4);
            f32x4 ev = *(const f32x4*)(bO + cf * 16 + khi * 4);
            z0[cf][0] = (acc0[cf].x - m0) * rs0 * gv.x + ev.x;
            z0[cf][1] = (acc0[cf].y - m0) * rs0 * gv.y + ev.y;
            z0[cf][2] = (acc0[cf].z - m0) * rs0 * gv.z + ev.z;
            z0[cf][3] = (acc0[cf].w - m0) * rs0 * gv.w + ev.w;
            z1[cf][0] = (acc1[cf].x - m1) * rs1 * gv.x + ev.x;
            z1[cf][1] = (acc1[cf].y - m1) * rs1 * gv.y + ev.y;
            z1[cf][2] = (acc1[cf].z - m1) * rs1 * gv.z + ev.z;
            z1[cf][3] = (acc1[cf].w - m1) * rs1 * gv.w + ev.w;
        }
    }

    if constexpr (FUSE_FINAL == 0) {
        #pragma unroll
        for (int cf = 0; cf < 8; ++cf) {
            if (r0 < Nn) {
                us4 ob = {f2bf(z0[cf][0]), f2bf(z0[cf][1]), f2bf(z0[cf][2]), f2bf(z0[cf][3])};
                *(us4*)(outb + (size_t)r0 * DD + cf * 16 + khi * 4) = ob;
            }
            if (r1 < Nn) {
                us4 ob = {f2bf(z1[cf][0]), f2bf(z1[cf][1]), f2bf(z1[cf][2]), f2bf(z1[cf][3])};
                *(us4*)(outb + (size_t)r1 * DD + cf * 16 + khi * 4) = ob;
            }
        }
    } else {
        #pragma unroll
        for (int cf = 0; cf < 8; ++cf) {
            us4 o0 = {f2bf(z0[cf][0]), f2bf(z0[cf][1]), f2bf(z0[cf][2]), f2bf(z0[cf][3])};
            us4 o1 = {f2bf(z1[cf][0]), f2bf(z1[cf][1]), f2bf(z1[cf][2]), f2bf(z1[cf][3])};
            int colb = (cf * 32 + khi * 8) ^ xw;
            *(us4*)(my + rlo * 256 + colb) = o0;
            *(us4*)(my + (16 + rlo) * 256 + colb) = o1;
        }
        bf16x8 fF0[8], fF1[8];
        #pragma unroll
        for (int ks = 0; ks < 4; ++ks) {
            fF0[ks] = *(const bf16x8*)(H1 + rr0 * DD + ks * 32 + khi * 8);
            fF1[ks] = *(const bf16x8*)(H1 + rr1 * DD + ks * 32 + khi * 8);
            int colb = (ks * 64 + khi * 16) ^ xw;
            fF0[4 + ks] = *(const bf16x8*)(my + rlo * 256 + colb);
            fF1[4 + ks] = *(const bf16x8*)(my + (16 + rlo) * 256 + colb);
        }
        f32x4 acc0[8], acc1[8];
        #pragma unroll
        for (int cf = 0; cf < 8; ++cf) {
            acc0[cf] = (f32x4){0.f, 0.f, 0.f, 0.f};
            acc1[cf] = (f32x4){0.f, 0.f, 0.f, 0.f};
        }
        #pragma unroll
        for (int cf = 0; cf < 8; ++cf) {
            #pragma unroll
            for (int ks = 0; ks < 8; ++ks) {
                bf16x8 wv = *(const bf16x8*)(WfL + ((size_t)(cf * 8 + ks) * 64 + lane) * 8);
                acc0[cf] = MFMA16(wv, fF0[ks], acc0[cf]);
                acc1[cf] = MFMA16(wv, fF1[ks], acc1[cf]);
            }
        }
        #pragma unroll
        for (int cf = 0; cf < 8; ++cf) {
            f32x4 bv = *(const f32x4*)(bL + cf * 16 + khi * 4);
            if (r0 < Nn) {
                f32x4 o;
                o.x = fmaxf(acc0[cf].x + bv.x, 0.f);
                o.y = fmaxf(acc0[cf].y + bv.y, 0.f);
                o.z = fmaxf(acc0[cf].z + bv.z, 0.f);
                o.w = fmaxf(acc0[cf].w + bv.w, 0.f);
                *(f32x4*)(outf + (size_t)r0 * DD + cf * 16 + khi * 4) = o;
            }
            if (r1 < Nn) {
                f32x4 o;
                o.x = fmaxf(acc1[cf].x + bv.x, 0.f);
                o.y = fmaxf(acc1[cf].y + bv.y, 0.f);
                o.z = fmaxf(acc1[cf].z + bv.z, 0.f);
                o.w = fmaxf(acc1[cf].w + bv.w, 0.f);
                *(f32x4*)(outf + (size_t)r1 * DD + cf * 16 + khi * 4) = o;
            }
        }
    }
}

extern "C" void kernel_launch(void* const* d_in, const int* in_sizes, int n_in,
                              void* d_out, int out_size, void* d_ws, size_t ws_size,
                              hipStream_t stream)
{
    const float* x    = (const float*)d_in[0];
    const int*   ei   = (const int*)d_in[1];
    const float* ea   = (const float*)d_in[2];
    const float* w1a  = (const float*)d_in[4];
    const float* b1a  = (const float*)d_in[5];
    const float* g1a  = (const float*)d_in[6];
    const float* be1a = (const float*)d_in[7];
    const float* w1b  = (const float*)d_in[8];
    const float* b1b  = (const float*)d_in[9];
    const float* w2a  = (const float*)d_in[10];
    const float* b2a  = (const float*)d_in[11];
    const float* g2a  = (const float*)d_in[12];
    const float* be2a = (const float*)d_in[13];
    const float* w2b  = (const float*)d_in[14];
    const float* b2b  = (const float*)d_in[15];
    const float* ng1  = (const float*)d_in[16];
    const float* nb1  = (const float*)d_in[17];
    const float* ng2  = (const float*)d_in[18];
    const float* nb2  = (const float*)d_in[19];
    const float* wl   = (const float*)d_in[20];
    const float* bl   = (const float*)d_in[21];

    const int N = in_sizes[0] / DD;
    const int E = in_sizes[1] / 2;
    const int* src = ei;
    const int* dst = ei + E;

    char* wp = (char*)d_ws;
    auto alloc = [&](size_t bytes) { void* p = wp; wp += (bytes + 255) & ~(size_t)255; return p; };
    unsigned short* aggb = (unsigned short*)alloc((size_t)N * DD * 2);
    unsigned short* xb   = (unsigned short*)alloc((size_t)N * DD * 2);
    unsigned short* h1b  = (unsigned short*)alloc((size_t)N * DD * 2);
    unsigned short* eab  = (unsigned short*)alloc((size_t)E * DD * 2);
    unsigned short* WfA1 = (unsigned short*)alloc(32768 * 2);
    unsigned short* WfB1 = (unsigned short*)alloc(32768 * 2);
    unsigned short* WfA2 = (unsigned short*)alloc(32768 * 2);
    unsigned short* WfB2 = (unsigned short*)alloc(32768 * 2);
    unsigned short* WfL  = (unsigned short*)alloc(32768 * 2);
    int* deg    = (int*)alloc((size_t)(N + 4) * 4);
    int* offs   = (int*)alloc((size_t)(N + 1) * 4);
    int* cursor = (int*)alloc((size_t)N * 4);
    int* bsum   = (int*)alloc(64 * 4);
    int* boff   = (int*)alloc(64 * 4);
    int* eids   = (int*)alloc((size_t)E * 4);
    int* srcs   = (int*)alloc((size_t)E * 4);

    const int nb = (N + 1023) / 1024;
    const int gE = (E + 255) / 256;
    const int gagg = (N + 3) / 4;
    const int gg = (N + 127) / 128;
    const int n8 = N * 16;
    const int gcvt = (n8 + 255) / 256;
    const int n4 = (N + 3) / 4;
    const int gz = (n4 + 255) / 256;

    setup_kernel<<<gz + gcvt + 80 + gE, 256, 0, stream>>>(
        deg, n4, x, xb, n8, w1a, w1b, w2a, w2b, wl,
        WfA1, WfB1, WfA2, WfB2, WfL, dst, E, gz, gcvt, 80);
    deg_blocksum<<<nb, 256, 0, stream>>>(deg, bsum, N);
    scan_bsums<<<1, 64, 0, stream>>>(bsum, boff, nb, offs, N);
    scan_final<<<nb, 256, 0, stream>>>(deg, boff, offs, cursor, N);
    fill_kernel<<<gE, 256, 0, stream>>>(src, dst, cursor, eids, srcs, E);

    // ---- conv1 (fused MLP) ----
    aggregate_conv1<<<gagg, 256, 0, stream>>>(xb, ea, eab, srcs, eids, offs, aggb, N);
    conv_fused<0><<<gg, 256, 0, stream>>>(aggb, WfA1, b1a, g1a, be1a,
                                          WfB1, b1b, ng1, nb1, h1b,
                                          nullptr, nullptr, nullptr, nullptr, N);

    // ---- conv2 (fused MLP + final linear) ----
    aggregate_conv2<<<gagg, 256, 0, stream>>>(h1b, eab, srcs, offs, aggb, N);
    conv_fused<1><<<gg, 256, 0, stream>>>(aggb, WfA2, b2a, g2a, be2a,
                                          WfB2, b2b, ng2, nb2, nullptr,
                                          h1b, WfL, bl, (float*)d_out, N);
}